// Round 8
// baseline (283.563 us; speedup 1.0000x reference)
//
#include <hip/hip_runtime.h>
#include <hip/hip_bf16.h>
#include <math.h>

#define BB 8
#define SS 2048
#define DD 1024
#define HH 16
#define DHH 64
#define NROWS (BB*SS)   // 16384
#define QSLICE ((size_t)BB * HH * SS)   // elems per qscore K-split slice

typedef unsigned short u16;
typedef __attribute__((ext_vector_type(8))) __bf16 bf16x8;
typedef __attribute__((ext_vector_type(4))) float f32x4;

__device__ __forceinline__ u16 f2bf(float f) {
    union { float f; unsigned u; } v; v.f = f;
    unsigned r = v.u + 0x7fffu + ((v.u >> 16) & 1u);
    return (u16)(r >> 16);
}
__device__ __forceinline__ float bf2f(u16 b) {
    union { unsigned u; float f; } v; v.u = ((unsigned)b) << 16;
    return v.f;
}

__device__ __forceinline__ void load_lds16(const void* g, void* l) {
    __builtin_amdgcn_global_load_lds(
        (const __attribute__((address_space(1))) unsigned int*)g,
        (__attribute__((address_space(3))) unsigned int*)l,
        16, 0, 0);
}

// raw workgroup barrier WITHOUT the vmcnt(0)/lgkmcnt(0) drain __syncthreads forces.
#define BAR() do { asm volatile("" ::: "memory"); \
                   __builtin_amdgcn_s_barrier();  \
                   asm volatile("" ::: "memory"); } while (0)

// ---------------- merged prep: cast + 3 weight transposes + wqa ----------------
__global__ __launch_bounds__(256)
void prep_kernel(const float* __restrict__ hs, u16* __restrict__ hs_bf,
                 const float* __restrict__ Wq, u16* __restrict__ WqT,
                 const float* __restrict__ Wk, u16* __restrict__ WkT,
                 const float* __restrict__ Wt, u16* __restrict__ WtT,
                 const float* __restrict__ Wqa, u16* __restrict__ WqaT) {
    __shared__ float tile[32][33];
    const int bid = blockIdx.x;
    const int t = threadIdx.x;
    if (bid < 16384) {
        int i = bid * 256 + t;
        float4 v = ((const float4*)hs)[i];
        ushort4 o;
        o.x = f2bf(v.x); o.y = f2bf(v.y); o.z = f2bf(v.z); o.w = f2bf(v.w);
        ((ushort4*)hs_bf)[i] = o;
        return;
    }
    if (bid < 19456) {
        int rel = bid - 16384;
        const float* W; u16* WT;
        if (rel < 1024)      { W = Wq; WT = WqT; }
        else if (rel < 2048) { W = Wk; WT = WkT; rel -= 1024; }
        else                 { W = Wt; WT = WtT; rel -= 2048; }
        int m0 = (rel & 31) * 32, k0 = (rel >> 5) * 32;
        int tx = t & 31, ty = t >> 5;
        #pragma unroll
        for (int i = 0; i < 4; i++) {
            int kk = ty + i * 8;
            tile[kk][tx] = W[(k0 + kk) * DD + m0 + tx];
        }
        __syncthreads();
        #pragma unroll
        for (int i = 0; i < 4; i++) {
            int mm = ty + i * 8;
            WT[(m0 + mm) * DD + k0 + tx] = f2bf(tile[tx][mm]);
        }
        return;
    }
    {
        int i = (bid - 19456) * 256 + t;
        int h = i >> 10, k = i & 1023;
        WqaT[i] = f2bf(Wqa[k * HH + h]);
    }
}

// ---------------- bf16 MFMA GEMM, 256x256 tile, BK=64, deep-pipelined 4-phase ----
// Staging plan (NEW): during iteration kt, stage tile kt+2 (same buffer parity!)
// into the regions of the CURRENT buffer as they retire:
//   B last read in p2 -> p3 stages B0,B1(kt+2) into cur-B
//   A last read in p3 -> p4 stages A0,A1(kt+2) into cur-A
// vmcnt(8) at p4-end drains exactly tile kt+1's 8 loads (issued last iteration),
// leaving tile kt+2's 8 loads in flight through ALL of iteration kt+1.
// Prologue: stage tiles 0+1 fully (16 loads), vmcnt(8) drains tile 0.
// Tail: vmcnt(0) at kt==14 (tile 15's loads must land; tile 16+ skipped).
template<int MODE>
__global__ __launch_bounds__(512, 2)
void gemm256_kernel(const u16* __restrict__ A, const u16* __restrict__ BT,
                    const float* __restrict__ b0, const float* __restrict__ b1,
                    const u16* __restrict__ res, float* __restrict__ Cf,
                    u16* __restrict__ C0, u16* __restrict__ C1,
                    const u16* __restrict__ WqaT, float* __restrict__ qraw) {
    __shared__ u16 smem[69632];
    const int by = blockIdx.y;
    const int row0 = blockIdx.x * 256;
    const int bcol0 = by * 256;
    const int colg0 = (MODE == 1) ? (bcol0 & 1023) : bcol0;
    const float* bias = (MODE == 1 && by >= 4) ? b1 : b0;
    u16* Cb = (MODE == 1 && by >= 4) ? C1 : C0;
    const u16* BTb = (MODE == 2) ? BT + ((size_t)(row0 >> 11) << 20) : BT;

    const int t = threadIdx.x;
    const int w = t >> 6, lane = t & 63;
    const int wm = w >> 2, wn = w & 3;
    const int m16 = lane & 15, quad = lane >> 4;

    f32x4 acc[8][4];
    #pragma unroll
    for (int i = 0; i < 8; i++)
        #pragma unroll
        for (int j = 0; j < 4; j++)
            acc[i][j] = (f32x4){0.f, 0.f, 0.f, 0.f};

    const int srow = t >> 3;
    const int scol = ((t & 7) ^ (srow & 7)) * 8;
    const u16* Ag = A + (size_t)(row0 + srow) * DD + scol;
    const u16* Bg = BTb + (size_t)(bcol0 + srow) * DD + scol;

    auto STAGE_H = [&](int ktile, int mat, int half) {
        if (ktile >= 16) return;
        const int buf = ktile & 1;
        const int k0 = ktile * 64;
        const u16* g = mat ? Bg : Ag;
        u16* s = smem + mat * 32768 + buf * 16384;
        #pragma unroll
        for (int j = 0; j < 2; ++j)
            load_lds16(g + k0 + (size_t)(half * 128 + j * 64) * DD,
                       s + half * 8192 + j * 4096 + t * 8);
    };

    // prologue: tiles 0 and 1 fully staged; drain tile 0 (8 oldest), keep tile 1 in flight.
    STAGE_H(0, 0, 0); STAGE_H(0, 0, 1); STAGE_H(0, 1, 0); STAGE_H(0, 1, 1);
    STAGE_H(1, 0, 0); STAGE_H(1, 0, 1); STAGE_H(1, 1, 0); STAGE_H(1, 1, 1);
    asm volatile("s_waitcnt vmcnt(8)" ::: "memory");
    BAR();

    for (int kt = 0; kt < 16; ++kt) {
        const int cur = kt & 1;
        const u16* sAc = smem + cur * 16384;
        const u16* sBc = smem + 32768 + cur * 16384;
        bf16x8 af[4][2], bfr[4][2];

        // ---------- phase 1: read af(lo rows) + bfr(ni 0-1); no staging
        #pragma unroll
        for (int mi = 0; mi < 4; ++mi)
            #pragma unroll
            for (int ks = 0; ks < 2; ++ks)
                af[mi][ks] = *(const bf16x8*)&sAc[(wm * 128 + mi * 16 + m16) * 64 +
                                                 (((ks * 4 + quad) ^ (m16 & 7)) * 8)];
        #pragma unroll
        for (int ni = 0; ni < 2; ++ni)
            #pragma unroll
            for (int ks = 0; ks < 2; ++ks)
                bfr[ni][ks] = *(const bf16x8*)&sBc[(wn * 64 + ni * 16 + m16) * 64 +
                                                   (((ks * 4 + quad) ^ (m16 & 7)) * 8)];
        BAR();
        __builtin_amdgcn_s_setprio(1);
        #pragma unroll
        for (int mi = 0; mi < 4; ++mi)
            #pragma unroll
            for (int ni = 0; ni < 2; ++ni)
                #pragma unroll
                for (int ks = 0; ks < 2; ++ks)
                    acc[mi][ni] = __builtin_amdgcn_mfma_f32_16x16x32_bf16(
                        bfr[ni][ks], af[mi][ks], acc[mi][ni], 0, 0, 0);
        __builtin_amdgcn_s_setprio(0);
        BAR();

        // ---------- phase 2: read bfr(ni 2-3) — last B reads of this tile
        #pragma unroll
        for (int ni = 2; ni < 4; ++ni)
            #pragma unroll
            for (int ks = 0; ks < 2; ++ks)
                bfr[ni][ks] = *(const bf16x8*)&sBc[(wn * 64 + ni * 16 + m16) * 64 +
                                                   (((ks * 4 + quad) ^ (m16 & 7)) * 8)];
        BAR();
        __builtin_amdgcn_s_setprio(1);
        #pragma unroll
        for (int mi = 0; mi < 4; ++mi)
            #pragma unroll
            for (int ni = 2; ni < 4; ++ni)
                #pragma unroll
                for (int ks = 0; ks < 2; ++ks)
                    acc[mi][ni] = __builtin_amdgcn_mfma_f32_16x16x32_bf16(
                        bfr[ni][ks], af[mi][ks], acc[mi][ni], 0, 0, 0);
        __builtin_amdgcn_s_setprio(0);
        BAR();

        // ---------- phase 3: read af(hi rows) — last A reads; stage (kt+2).B into cur-B
        #pragma unroll
        for (int mi = 0; mi < 4; ++mi)
            #pragma unroll
            for (int ks = 0; ks < 2; ++ks)
                af[mi][ks] = *(const bf16x8*)&sAc[(wm * 128 + (4 + mi) * 16 + m16) * 64 +
                                                 (((ks * 4 + quad) ^ (m16 & 7)) * 8)];
        STAGE_H(kt + 2, 1, 0);
        STAGE_H(kt + 2, 1, 1);
        BAR();
        __builtin_amdgcn_s_setprio(1);
        #pragma unroll
        for (int mi = 0; mi < 4; ++mi)
            #pragma unroll
            for (int ni = 0; ni < 2; ++ni)
                #pragma unroll
                for (int ks = 0; ks < 2; ++ks)
                    acc[4 + mi][ni] = __builtin_amdgcn_mfma_f32_16x16x32_bf16(
                        bfr[ni][ks], af[mi][ks], acc[4 + mi][ni], 0, 0, 0);
        __builtin_amdgcn_s_setprio(0);
        BAR();

        // ---------- phase 4: stage (kt+2).A into cur-A; counted drain of tile kt+1
        STAGE_H(kt + 2, 0, 0);
        STAGE_H(kt + 2, 0, 1);
        BAR();
        __builtin_amdgcn_s_setprio(1);
        #pragma unroll
        for (int mi = 0; mi < 4; ++mi)
            #pragma unroll
            for (int ni = 2; ni < 4; ++ni)
                #pragma unroll
                for (int ks = 0; ks < 2; ++ks)
                    acc[4 + mi][ni] = __builtin_amdgcn_mfma_f32_16x16x32_bf16(
                        bfr[ni][ks], af[mi][ks], acc[4 + mi][ni], 0, 0, 0);
        __builtin_amdgcn_s_setprio(0);
        if (kt < 14) asm volatile("s_waitcnt vmcnt(8)" ::: "memory");
        else         asm volatile("s_waitcnt vmcnt(0)" ::: "memory");
        BAR();
    }

    u16* sC = smem;
    #pragma unroll
    for (int mi = 0; mi < 8; ++mi) {
        const int lrow = wm * 128 + mi * 16 + m16;
        #pragma unroll
        for (int ni = 0; ni < 4; ++ni) {
            const int lcol = wn * 64 + ni * 16 + quad * 4;
            const float4 bv = *(const float4*)&bias[colg0 + lcol];
            if (MODE == 1) {
                ushort4 o;
                o.x = f2bf(acc[mi][ni][0] + bv.x);
                o.y = f2bf(acc[mi][ni][1] + bv.y);
                o.z = f2bf(acc[mi][ni][2] + bv.z);
                o.w = f2bf(acc[mi][ni][3] + bv.w);
                *(ushort4*)&sC[(size_t)lrow * 272 + lcol] = o;
            } else {
                const size_t idx = (size_t)(row0 + lrow) * DD + colg0 + lcol;
                const ushort4 rv = *(const ushort4*)&res[idx];
                float4 o;
                o.x = acc[mi][ni][0] + bv.x + bf2f(rv.x);
                o.y = acc[mi][ni][1] + bv.y + bf2f(rv.y);
                o.z = acc[mi][ni][2] + bv.z + bf2f(rv.z);
                o.w = acc[mi][ni][3] + bv.w + bf2f(rv.w);
                *(float4*)&Cf[idx] = o;
            }
        }
    }
    if (MODE == 1) {
        __syncthreads();
        #pragma unroll
        for (int it = 0; it < 16; ++it) {
            const int r = it * 16 + (t >> 5);
            const int c = t & 31;
            uint4 v = *(const uint4*)&sC[(size_t)r * 272 + c * 8];
            *(uint4*)&Cb[(size_t)(row0 + r) * DD + colg0 + c * 8] = v;
        }
        if (by < 4) {
            const int bIdx = row0 >> 11;
            bf16x8 wq[8];
            const u16* bp = WqaT + (size_t)m16 * DD + by * 256 + quad * 8;
            #pragma unroll
            for (int kk = 0; kk < 8; ++kk) wq[kk] = *(const bf16x8*)(bp + kk * 32);
            #pragma unroll
            for (int rt = 0; rt < 2; ++rt) {
                const int sr = (w * 2 + rt) * 16;
                f32x4 qa = (f32x4){0.f, 0.f, 0.f, 0.f};
                #pragma unroll
                for (int kk = 0; kk < 8; ++kk) {
                    bf16x8 a = *(const bf16x8*)&sC[(size_t)(sr + m16) * 272 + quad * 8 + kk * 32];
                    qa = __builtin_amdgcn_mfma_f32_16x16x32_bf16(a, wq[kk], qa, 0, 0, 0);
                }
                #pragma unroll
                for (int r = 0; r < 4; ++r) {
                    int s = (row0 & 2047) + sr + quad * 4 + r;
                    qraw[((size_t)(by * BB + bIdx) * HH + m16) * SS + s] = qa[r];
                }
            }
        }
    }
}

// ---------------- fused middle v2: 1024 threads, vectorized, shuffle-reduced ------
__global__ __launch_bounds__(1024)
void attnmid_kernel(const float* __restrict__ qraw, const float* __restrict__ bqa,
                    const float* __restrict__ mask, const u16* __restrict__ qbf,
                    const u16* __restrict__ kbf, float* __restrict__ pk) {
    const int bh = blockIdx.x;
    const int b = bh >> 4, h = bh & 15;
    const int t = threadIdx.x;
    const int wid = t >> 6, lane = t & 63;
    const int sub = lane & 7;
    const int srw = lane >> 3;

    __shared__ float sw[SS];
    __shared__ float redM[16], redS[16];
    __shared__ float prr[16][64];
    __shared__ float pql[64];

    // ---- phase 1: softmax of q attention logits ----
    {
        const float* qr = qraw + ((size_t)bh << 11);
        const float bq_ = bqa[h];
        float x0 = qr[t] + qr[t + QSLICE] + qr[t + 2 * QSLICE] + qr[t + 3 * QSLICE];
        float x1 = qr[t + 1024] + qr[t + 1024 + QSLICE] + qr[t + 1024 + 2 * QSLICE]
                 + qr[t + 1024 + 3 * QSLICE];
        x0 = (x0 + bq_) * 0.125f + mask[b * SS + t];
        x1 = (x1 + bq_) * 0.125f + mask[b * SS + t + 1024];
        float m = fmaxf(x0, x1);
        #pragma unroll
        for (int o = 32; o; o >>= 1) m = fmaxf(m, __shfl_xor(m, o));
        if (lane == 0) redM[wid] = m;
        __syncthreads();
        m = redM[0];
        #pragma unroll
        for (int i = 1; i < 16; i++) m = fmaxf(m, redM[i]);
        float e0 = __expf(x0 - m), e1 = __expf(x1 - m);
        float sum = e0 + e1;
        #pragma unroll
        for (int o = 32; o; o >>= 1) sum += __shfl_xor(sum, o);
        if (lane == 0) redS[wid] = sum;
        __syncthreads();
        float tot = 0.f;
        #pragma unroll
        for (int i = 0; i < 16; i++) tot += redS[i];
        float inv = 1.0f / tot;
        sw[t] = e0 * inv;
        sw[t + 1024] = e1 * inv;
        __syncthreads();
    }

    // ---- phase 2: pool q -> pql[64] ----
    {
        const u16* qb = qbf + (((size_t)b * SS) << 10) + h * 64 + sub * 8;
        float a[8];
        #pragma unroll
        for (int j = 0; j < 8; j++) a[j] = 0.f;
        #pragma unroll
        for (int it = 0; it < 16; ++it) {
            int s = it * 128 + wid * 8 + srw;
            uint4 kv = *(const uint4*)(qb + ((size_t)s << 10));
            float wf = sw[s];
            unsigned ww[4] = {kv.x, kv.y, kv.z, kv.w};
            #pragma unroll
            for (int j = 0; j < 4; j++) {
                union { unsigned u; float f; } lo, hi;
                lo.u = ww[j] << 16; hi.u = ww[j] & 0xffff0000u;
                a[2 * j]     += wf * lo.f;
                a[2 * j + 1] += wf * hi.f;
            }
        }
        #pragma unroll
        for (int o = 8; o <= 32; o <<= 1)
            #pragma unroll
            for (int j = 0; j < 8; j++) a[j] += __shfl_xor(a[j], o);
        if (srw == 0)
            #pragma unroll
            for (int j = 0; j < 8; j++) prr[wid][sub * 8 + j] = a[j];
        __syncthreads();
        if (t < 64) {
            float s2 = 0.f;
            #pragma unroll
            for (int w2 = 0; w2 < 16; w2++) s2 += prr[w2][t];
            pql[t] = s2;
        }
        __syncthreads();
    }

    // ---- phase 3: raw qk scores (s-major, coalesced), then softmax ----
    {
        const u16* kb = kbf + (((size_t)b * SS) << 10) + h * 64 + sub * 8;
        float pqr[8];
        #pragma unroll
        for (int j = 0; j < 8; j++) pqr[j] = pql[sub * 8 + j];
        #pragma unroll
        for (int it = 0; it < 16; ++it) {
            int s = it * 128 + wid * 8 + srw;
            uint4 kv = *(const uint4*)(kb + ((size_t)s << 10));
            unsigned ww[4] = {kv.x, kv.y, kv.z, kv.w};
            float d = 0.f;
            #pragma unroll
            for (int j = 0; j < 4; j++) {
                union { unsigned u; float f; } lo, hi;
                lo.u = ww[j] << 16; hi.u = ww[j] & 0xffff0000u;
                d += lo.f * pqr[2 * j] + hi.f * pqr[2 * j + 1];
            }
            d += __shfl_xor(d, 1);
            d += __shfl_xor(d, 2);
            d += __shfl_xor(d, 4);
            if (sub == 0) sw[s] = d * 0.125f + mask[b * SS + s];
        }
        __syncthreads();
        float x0 = sw[t], x1 = sw[t + 1024];
        float m = fmaxf(x0, x1);
        #pragma unroll
        for (int o = 32; o; o >>= 1) m = fmaxf(m, __shfl_xor(m, o));
        if (lane == 0) redM[wid] = m;
        __syncthreads();
        m = redM[0];
        #pragma unroll
        for (int i = 1; i < 16; i++) m = fmaxf(m, redM[i]);
        float e0 = __expf(x0 - m), e1 = __expf(x1 - m);
        float sum = e0 + e1;
        #pragma unroll
        for (int o = 32; o; o >>= 1) sum += __shfl_xor(sum, o);
        if (lane == 0) redS[wid] = sum;
        __syncthreads();
        float tot = 0.f;
        #pragma unroll
        for (int i = 0; i < 16; i++) tot += redS[i];
        float inv = 1.0f / tot;
        sw[t] = e0 * inv;
        sw[t + 1024] = e1 * inv;
        __syncthreads();
    }

    // ---- phase 4: pool k -> pk[b, h*64 + d] ----
    {
        const u16* kb = kbf + (((size_t)b * SS) << 10) + h * 64 + sub * 8;
        float a[8];
        #pragma unroll
        for (int j = 0; j < 8; j++) a[j] = 0.f;
        #pragma unroll
        for (int it = 0; it < 16; ++it) {
            int s = it * 128 + wid * 8 + srw;
            uint4 kv = *(const uint4*)(kb + ((size_t)s << 10));
            float wf = sw[s];
            unsigned ww[4] = {kv.x, kv.y, kv.z, kv.w};
            #pragma unroll
            for (int j = 0; j < 4; j++) {
                union { unsigned u; float f; } lo, hi;
                lo.u = ww[j] << 16; hi.u = ww[j] & 0xffff0000u;
                a[2 * j]     += wf * lo.f;
                a[2 * j + 1] += wf * hi.f;
            }
        }
        #pragma unroll
        for (int o = 8; o <= 32; o <<= 1)
            #pragma unroll
            for (int j = 0; j < 8; j++) a[j] += __shfl_xor(a[j], o);
        if (srw == 0)
            #pragma unroll
            for (int j = 0; j < 8; j++) prr[wid][sub * 8 + j] = a[j];
        __syncthreads();
        if (t < 64) {
            float s2 = 0.f;
            #pragma unroll
            for (int w2 = 0; w2 < 16; w2++) s2 += prr[w2][t];
            pk[b * DD + h * 64 + t] = s2;
        }
    }
}

// ---------------- WtT8[b][n][k] = bf16( WtT[n][k] * pk[b][k] ) ----------------
__global__ __launch_bounds__(256)
void wtscale_kernel(const u16* __restrict__ WtT, const float* __restrict__ pk,
                    u16* __restrict__ WtT8) {
    size_t i = (size_t)blockIdx.x * 256 + threadIdx.x;   // < 1048576
    int b = (int)(i >> 17);
    size_t off = (i & 131071) << 3;
    int d = (int)(off & 1023);
    const float4 p0 = *(const float4*)&pk[b * 1024 + d];
    const float4 p1 = *(const float4*)&pk[b * 1024 + d + 4];
    ushort4 a0 = ((const ushort4*)(WtT + off))[0];
    ushort4 a1 = ((const ushort4*)(WtT + off))[1];
    ushort4 o0, o1;
    o0.x = f2bf(bf2f(a0.x) * p0.x); o0.y = f2bf(bf2f(a0.y) * p0.y);
    o0.z = f2bf(bf2f(a0.z) * p0.z); o0.w = f2bf(bf2f(a0.w) * p0.w);
    o1.x = f2bf(bf2f(a1.x) * p1.x); o1.y = f2bf(bf2f(a1.y) * p1.y);
    o1.z = f2bf(bf2f(a1.z) * p1.z); o1.w = f2bf(bf2f(a1.w) * p1.w);
    u16* dst = WtT8 + ((size_t)b << 20) + off;
    ((ushort4*)dst)[0] = o0;
    ((ushort4*)dst)[1] = o1;
}

extern "C" void kernel_launch(void* const* d_in, const int* in_sizes, int n_in,
                              void* d_out, int out_size, void* d_ws, size_t ws_size,
                              hipStream_t stream) {
    const float* hs   = (const float*)d_in[0];
    const float* mask = (const float*)d_in[1];
    const float* Wq   = (const float*)d_in[2];
    const float* bq   = (const float*)d_in[3];
    const float* Wqa  = (const float*)d_in[4];
    const float* bqa  = (const float*)d_in[5];
    const float* Wk   = (const float*)d_in[6];
    const float* bk   = (const float*)d_in[7];
    const float* Wt   = (const float*)d_in[8];
    const float* bt   = (const float*)d_in[9];
    float* out = (float*)d_out;

    char* ws = (char*)d_ws;
    u16*   hs_bf = (u16*)ws;   ws += (size_t)NROWS * DD * 2;
    u16*   WqT   = (u16*)ws;   ws += (size_t)DD * DD * 2;
    u16*   WkT   = (u16*)ws;   ws += (size_t)DD * DD * 2;   // adjacent to WqT (merged GEMM)
    u16*   WtT   = (u16*)ws;   ws += (size_t)DD * DD * 2;
    u16*   WqaT  = (u16*)ws;   ws += (size_t)HH * DD * 2;
    u16*   q_bf  = (u16*)ws;   ws += (size_t)NROWS * DD * 2;
    u16*   k_bf  = (u16*)ws;   ws += (size_t)NROWS * DD * 2;
    float* qraw  = (float*)ws; ws += QSLICE * 4 * 4;
    float* pk    = (float*)ws; ws += (size_t)BB * HH * 64 * 4;
    u16*   WtT8  = hs_bf;  // alias: hs_bf dead after merged QK gemm

    prep_kernel<<<19520, 256, 0, stream>>>(hs, hs_bf, Wq, WqT, Wk, WkT, Wt, WtT,
                                           Wqa, WqaT);

    gemm256_kernel<1><<<dim3(NROWS / 256, 8), 512, 0, stream>>>(
        hs_bf, WqT, bq, bk, nullptr, nullptr, q_bf, k_bf, WqaT, qraw);

    attnmid_kernel<<<BB * HH, 1024, 0, stream>>>(qraw, bqa, mask, q_bf, k_bf, pk);

    wtscale_kernel<<<4096, 256, 0, stream>>>(WtT, pk, WtT8);

    gemm256_kernel<2><<<dim3(NROWS / 256, 4), 512, 0, stream>>>(
        q_bf, WtT8, bt, nullptr, q_bf, out, nullptr, nullptr, nullptr, nullptr);
}